// Round 5
// baseline (32.775 us; speedup 1.0000x reference)
//
#include <hip/hip_runtime.h>
#include <hip/hip_bf16.h>

// B=16, N=100, D=256, C=2, E=N*(N-1)=9900.
// Complete-graph GCN collapses to a per-batch MLP:
//   gcn_conv(x) = mean_n(x) @ W + b  (deg==100, norm==1/100, incl. self-loop)
// R4: ONE fused kernel, grid 128 = (16 b x 8 col-slices). Each block computes
// only its 32-col slice of z1/z2/h (W1/8+W2/8+Wl1/8 = 128KB vs R3's 576KB),
// exchanging slices via d_ws with device-scope release/acquire barriers
// (8 participants per batch; 128 blocks <= 256 CUs => co-residency guaranteed,
// deadlock-free by capacity). Counters zeroed by a tiny memset node each
// launch (replay/poison-safe). All reductions fixed-order => deterministic.

#define BB 16
#define NN 100
#define DD 256
#define EE 9900
#define CHUNK 1238          // ceil(EE/8)

// ws float offsets (counters occupy bytes [0,192))
#define WSF_LG 64           // [16][8][2] partial logits
#define WSF_Z1 1024         // [16][256]
#define WSF_Z2 5120         // [16][256]

__device__ __forceinline__ void barrier8(unsigned* cnt, int t) {
    __syncthreads();        // all waves' prior global stores drained (vmcnt 0)
    if (t == 0) {
        __hip_atomic_fetch_add(cnt, 1u, __ATOMIC_RELEASE, __HIP_MEMORY_SCOPE_AGENT);
        int guard = 0;
        while (__hip_atomic_load(cnt, __ATOMIC_ACQUIRE, __HIP_MEMORY_SCOPE_AGENT) < 8u
               && ++guard < 4000000) { }
    }
    __syncthreads();
}

__global__ __launch_bounds__(256) void k_fused(
    const float* __restrict__ x,        // [B,N,D]
    const float* __restrict__ bboxes,   // [B,N,4]
    const int*   __restrict__ edge,     // [2,E]
    const float* __restrict__ W1, const float* __restrict__ b1,
    const float* __restrict__ W2, const float* __restrict__ b2,
    const float* __restrict__ Wl1, const float* __restrict__ bl1,
    const float* __restrict__ Wf, const float* __restrict__ bf,
    float* __restrict__ ws, float* __restrict__ out)
{
    const int b = blockIdx.x >> 3;
    const int g = blockIdx.x & 7;
    const int t = threadIdx.x;
    const int kq = t >> 5;          // 0..7
    const int cl = t & 31;          // 0..31
    const int c  = g * 32 + cl;     // this block's output column for (kq,cl)

    unsigned* cnt = (unsigned*)ws;

    __shared__ __align__(16) float sX[DD];   // xbar -> z1(full) -> z2(full)
    __shared__ float4 sP4[4][64];
    __shared__ float  sP[8][32];
    __shared__ float  sL0[32], sL1[32];
    __shared__ float  sp01[2];

    // ---- P0: xbar (local, redundant per block): 4 node-groups x 64 d-quads ----
    {
        const float* xp = x + (size_t)b * NN * DD + (size_t)(t >> 6) * 25 * DD + (t & 63) * 4;
        float4 a = {0.f, 0.f, 0.f, 0.f};
        #pragma unroll
        for (int n = 0; n < 25; ++n) {
            float4 v = *(const float4*)(xp + (size_t)n * DD);
            a.x += v.x; a.y += v.y; a.z += v.z; a.w += v.w;
        }
        sP4[t >> 6][t & 63] = a;
    }
    __syncthreads();
    if (t < 64) {
        float4 s0 = sP4[0][t], s1 = sP4[1][t], s2 = sP4[2][t], s3 = sP4[3][t];
        float4 r;
        r.x = (s0.x + s1.x + s2.x + s3.x) * 0.01f;
        r.y = (s0.y + s1.y + s2.y + s3.y) * 0.01f;
        r.z = (s0.z + s1.z + s2.z + s3.z) * 0.01f;
        r.w = (s0.w + s1.w + s2.w + s3.w) * 0.01f;
        *(float4*)&sX[t * 4] = r;
    }
    __syncthreads();

    // ---- P1: z1 slice = relu(xbar @ W1[:, 32g:32g+32] + b1) ----
    {
        const float* Wp = W1 + (size_t)(kq * 32) * DD + c;
        const float* xk = sX + kq * 32;
        float acc = 0.f;
        #pragma unroll
        for (int k = 0; k < 32; ++k) acc = fmaf(xk[k], Wp[(size_t)k * DD], acc);
        sP[kq][cl] = acc;
        __syncthreads();
        if (t < 32) {
            float s = b1[g * 32 + t];
            #pragma unroll
            for (int q = 0; q < 8; ++q) s += sP[q][t];
            ws[WSF_Z1 + b * DD + g * 32 + t] = fmaxf(s, 0.f);
        }
    }
    barrier8(cnt + 0 * 16 + b, t);
    sX[t] = ws[WSF_Z1 + b * DD + t];        // full z1
    __syncthreads();

    // ---- P2: z2 slice = relu(z1 @ W2[:, slice] + b2) ----
    {
        const float* Wp = W2 + (size_t)(kq * 32) * DD + c;
        const float* xk = sX + kq * 32;
        float acc = 0.f;
        #pragma unroll
        for (int k = 0; k < 32; ++k) acc = fmaf(xk[k], Wp[(size_t)k * DD], acc);
        __syncthreads();                    // sP reuse guard
        sP[kq][cl] = acc;
        __syncthreads();
        if (t < 32) {
            float s = b2[g * 32 + t];
            #pragma unroll
            for (int q = 0; q < 8; ++q) s += sP[q][t];
            ws[WSF_Z2 + b * DD + g * 32 + t] = fmaxf(s, 0.f);
        }
    }
    barrier8(cnt + 1 * 16 + b, t);
    sX[t] = ws[WSF_Z2 + b * DD + t];        // full z2
    __syncthreads();

    // ---- P3: h slice = relu(z2 @ (Wl1_top+Wl1_bot)[:, slice] + bl1),
    //          then partial logits over this slice ----
    {
        const float* Wp0 = Wl1 + (size_t)(kq * 32) * DD + c;
        const float* Wp1 = Wp0 + (size_t)DD * DD;
        const float* xk = sX + kq * 32;
        float acc = 0.f;
        #pragma unroll
        for (int k = 0; k < 32; ++k)
            acc = fmaf(xk[k], Wp0[(size_t)k * DD] + Wp1[(size_t)k * DD], acc);
        __syncthreads();
        sP[kq][cl] = acc;
        __syncthreads();
        if (t < 32) {
            const int cc = g * 32 + t;
            float s = bl1[cc];
            #pragma unroll
            for (int q = 0; q < 8; ++q) s += sP[q][t];
            float h = fmaxf(s, 0.f);
            sL0[t] = h * Wf[cc * 2 + 0];
            sL1[t] = h * Wf[cc * 2 + 1];
        }
        __syncthreads();
        if (t == 0) {
            float l0 = 0.f, l1 = 0.f;
            #pragma unroll
            for (int i = 0; i < 32; ++i) { l0 += sL0[i]; l1 += sL1[i]; }
            ws[WSF_LG + (b * 8 + g) * 2 + 0] = l0;
            ws[WSF_LG + (b * 8 + g) * 2 + 1] = l1;
        }
    }
    barrier8(cnt + 2 * 16 + b, t);

    // ---- logits assembly (fixed order => deterministic) + log_softmax ----
    if (t == 0) {
        float L0 = bf[0], L1 = bf[1];
        #pragma unroll
        for (int q = 0; q < 8; ++q) {
            L0 += ws[WSF_LG + (b * 8 + q) * 2 + 0];
            L1 += ws[WSF_LG + (b * 8 + q) * 2 + 1];
        }
        float m  = fmaxf(L0, L1);
        float ls = logf(expf(L0 - m) + expf(L1 - m));
        sp01[0] = L0 - m - ls;
        sp01[1] = L1 - m - ls;
    }
    __syncthreads();

    // ---- P4: output — this block writes edges [g*CHUNK, min(+CHUNK, E)) ----
    {
        const float p0 = sp01[0], p1 = sp01[1];
        const int e1 = min(g * CHUNK + CHUNK, EE);
        float2* out2 = (float2*)out;
        float4* bout = (float4*)(out + (size_t)BB * EE * 2);
        for (int e = g * CHUNK + t; e < e1; e += 256) {
            const int idx = b * EE + e;
            const int s   = edge[e];
            const int d2  = edge[EE + e];
            float2 p; p.x = p0; p.y = p1;
            out2[idx] = p;
            const float4 bs = *(const float4*)(bboxes + (size_t)(b * NN + s) * 4);
            const float4 bd = *(const float4*)(bboxes + (size_t)(b * NN + d2) * 4);
            bout[idx * 2 + 0] = bs;
            bout[idx * 2 + 1] = bd;
        }
    }
}

extern "C" void kernel_launch(void* const* d_in, const int* in_sizes, int n_in,
                              void* d_out, int out_size, void* d_ws, size_t ws_size,
                              hipStream_t stream) {
    const float* hidden  = (const float*)d_in[0];
    const float* bboxes  = (const float*)d_in[1];
    const float* W1      = (const float*)d_in[2];
    const float* b1      = (const float*)d_in[3];
    const float* W2      = (const float*)d_in[4];
    const float* b2      = (const float*)d_in[5];
    const float* Wl1     = (const float*)d_in[6];
    const float* bl1     = (const float*)d_in[7];
    const float* Wf      = (const float*)d_in[8];
    const float* bf      = (const float*)d_in[9];
    const int*   edge    = (const int*)d_in[10];

    // zero the 3x16 barrier counters (poison/replay-safe)
    hipMemsetAsync(d_ws, 0, 192, stream);

    k_fused<<<BB * 8, 256, 0, stream>>>(hidden, bboxes, edge,
                                        W1, b1, W2, b2, Wl1, bl1, Wf, bf,
                                        (float*)d_ws, (float*)d_out);
}

// Round 6
// 18.236 us; speedup vs baseline: 1.7972x; 1.7972x over previous
//
#include <hip/hip_runtime.h>
#include <hip/hip_bf16.h>

// B=16, N=100, D=256, C=2, E=N*(N-1)=9900.
// Complete-graph GCN collapses to a per-batch MLP:
//   gcn_conv(x) = mean_n(x) @ W + b  (deg==100, norm==1/100, incl. self-loop)
// R5: ONE node, zero sync, full redundancy. Grid 256 = (16 b x 16 chunks),
// 1 block/CU. Each block recomputes the whole MLP for its batch (x 102KB +
// W1 256KB + W2 256KB + Wl1 512KB streamed at port BW) and writes 1/16 of
// that batch's edges. bbox-pair writes (logits-independent) are hoisted to
// the top to overlap with the weight streams. Calibration from R1-R4:
// node OH ~3.2us, in-kernel cross-block barrier ~8us (NEVER), per-CU L2
// stream ~104-150 GB/s => redundant streaming beats any exchange scheme.

#define BB 16
#define NN 100
#define DD 256
#define EE 9900
#define GG 16
#define CHUNK 619           // ceil(EE/GG)

__global__ __launch_bounds__(512) void k_all(
    const float* __restrict__ x,        // [B,N,D]
    const float* __restrict__ bboxes,   // [B,N,4]
    const int*   __restrict__ edge,     // [2,E]
    const float* __restrict__ W1, const float* __restrict__ b1,
    const float* __restrict__ W2, const float* __restrict__ b2,
    const float* __restrict__ Wl1, const float* __restrict__ bl1,
    const float* __restrict__ Wf, const float* __restrict__ bf,
    float* __restrict__ out)
{
    const int b  = blockIdx.x >> 4;
    const int g  = blockIdx.x & 15;
    const int t  = threadIdx.x;
    const int kq = t >> 6;          // 0..7 (k-slice / node-group)
    const int c4 = t & 63;          // column quad 0..63

    __shared__ __align__(16) float sX[DD];
    __shared__ __align__(16) float sY[DD];
    __shared__ float4 sP4[8][64];
    __shared__ float r0[4], r1[4];
    __shared__ float sp01[2];

    const int e0 = g * CHUNK;
    const int e1 = min(e0 + CHUNK, EE);

    // ---- P0: xbar partials (8 node-groups: 13,13,13,13,12,12,12,12) ----
    {
        const int start = kq * 12 + (kq < 4 ? kq : 4);
        const int cnt   = (kq < 4) ? 13 : 12;
        const float* xp = x + ((size_t)b * NN + start) * DD + c4 * 4;
        float4 a = {0.f, 0.f, 0.f, 0.f};
        #pragma unroll
        for (int n = 0; n < 13; ++n) {
            if (n < cnt) {
                float4 v = *(const float4*)(xp + (size_t)n * DD);
                a.x += v.x; a.y += v.y; a.z += v.z; a.w += v.w;
            }
        }
        sP4[kq][c4] = a;
    }

    // ---- bbox-pair writes (independent of MLP) — fill the load bubble ----
    {
        float4* bout = (float4*)(out + (size_t)BB * EE * 2);
        for (int e = e0 + t; e < e1; e += 512) {
            const int s   = edge[e];
            const int d2  = edge[EE + e];
            const size_t idx = (size_t)b * EE + e;
            bout[idx * 2 + 0] = *(const float4*)(bboxes + (size_t)(b * NN + s) * 4);
            bout[idx * 2 + 1] = *(const float4*)(bboxes + (size_t)(b * NN + d2) * 4);
        }
    }
    __syncthreads();
    if (t < 64) {
        float4 s = sP4[0][t];
        #pragma unroll
        for (int q = 1; q < 8; ++q) {
            float4 p = sP4[q][t];
            s.x += p.x; s.y += p.y; s.z += p.z; s.w += p.w;
        }
        float4 r;
        r.x = s.x * 0.01f; r.y = s.y * 0.01f; r.z = s.z * 0.01f; r.w = s.w * 0.01f;
        ((float4*)sX)[t] = r;
    }
    __syncthreads();

    // ---- layer 1: sY = relu(sX @ W1 + b1) ----
    {
        const float* Wp = W1 + (size_t)(kq * 32) * DD + c4 * 4;
        const float* xk = sX + kq * 32;
        float4 acc = {0.f, 0.f, 0.f, 0.f};
        #pragma unroll 8
        for (int k = 0; k < 32; ++k) {
            float4 w = *(const float4*)(Wp + (size_t)k * DD);
            float xv = xk[k];
            acc.x = fmaf(xv, w.x, acc.x); acc.y = fmaf(xv, w.y, acc.y);
            acc.z = fmaf(xv, w.z, acc.z); acc.w = fmaf(xv, w.w, acc.w);
        }
        __syncthreads();                // sP4 free (xbar finalize done)
        sP4[kq][c4] = acc;
        __syncthreads();
        if (t < 64) {
            float4 s = sP4[0][t];
            #pragma unroll
            for (int q = 1; q < 8; ++q) {
                float4 p = sP4[q][t];
                s.x += p.x; s.y += p.y; s.z += p.z; s.w += p.w;
            }
            float4 bs = *(const float4*)(b1 + t * 4);
            float4 r;
            r.x = fmaxf(s.x + bs.x, 0.f); r.y = fmaxf(s.y + bs.y, 0.f);
            r.z = fmaxf(s.z + bs.z, 0.f); r.w = fmaxf(s.w + bs.w, 0.f);
            ((float4*)sY)[t] = r;
        }
        __syncthreads();
    }

    // ---- layer 2: sX = relu(sY @ W2 + b2) ----
    {
        const float* Wp = W2 + (size_t)(kq * 32) * DD + c4 * 4;
        const float* xk = sY + kq * 32;
        float4 acc = {0.f, 0.f, 0.f, 0.f};
        #pragma unroll 8
        for (int k = 0; k < 32; ++k) {
            float4 w = *(const float4*)(Wp + (size_t)k * DD);
            float xv = xk[k];
            acc.x = fmaf(xv, w.x, acc.x); acc.y = fmaf(xv, w.y, acc.y);
            acc.z = fmaf(xv, w.z, acc.z); acc.w = fmaf(xv, w.w, acc.w);
        }
        __syncthreads();
        sP4[kq][c4] = acc;
        __syncthreads();
        if (t < 64) {
            float4 s = sP4[0][t];
            #pragma unroll
            for (int q = 1; q < 8; ++q) {
                float4 p = sP4[q][t];
                s.x += p.x; s.y += p.y; s.z += p.z; s.w += p.w;
            }
            float4 bs = *(const float4*)(b2 + t * 4);
            float4 r;
            r.x = fmaxf(s.x + bs.x, 0.f); r.y = fmaxf(s.y + bs.y, 0.f);
            r.z = fmaxf(s.z + bs.z, 0.f); r.w = fmaxf(s.w + bs.w, 0.f);
            ((float4*)sX)[t] = r;
        }
        __syncthreads();
    }

    // ---- layer 3: sY = relu(sX @ (Wl1_top + Wl1_bot) + bl1) ----
    {
        const float* Wp0 = Wl1 + (size_t)(kq * 32) * DD + c4 * 4;
        const float* Wp1 = Wp0 + (size_t)DD * DD;
        const float* xk = sX + kq * 32;
        float4 acc = {0.f, 0.f, 0.f, 0.f};
        #pragma unroll 4
        for (int k = 0; k < 32; ++k) {
            float4 w0 = *(const float4*)(Wp0 + (size_t)k * DD);
            float4 w1 = *(const float4*)(Wp1 + (size_t)k * DD);
            float xv = xk[k];
            acc.x = fmaf(xv, w0.x + w1.x, acc.x);
            acc.y = fmaf(xv, w0.y + w1.y, acc.y);
            acc.z = fmaf(xv, w0.z + w1.z, acc.z);
            acc.w = fmaf(xv, w0.w + w1.w, acc.w);
        }
        __syncthreads();
        sP4[kq][c4] = acc;
        __syncthreads();
        if (t < 64) {
            float4 s = sP4[0][t];
            #pragma unroll
            for (int q = 1; q < 8; ++q) {
                float4 p = sP4[q][t];
                s.x += p.x; s.y += p.y; s.z += p.z; s.w += p.w;
            }
            float4 bs = *(const float4*)(bl1 + t * 4);
            float4 r;
            r.x = fmaxf(s.x + bs.x, 0.f); r.y = fmaxf(s.y + bs.y, 0.f);
            r.z = fmaxf(s.z + bs.z, 0.f); r.w = fmaxf(s.w + bs.w, 0.f);
            ((float4*)sY)[t] = r;
        }
        __syncthreads();
    }

    // ---- logits + log_softmax ----
    if (t < DD) {
        float hv = sY[t];
        float l0 = hv * Wf[t * 2 + 0];
        float l1 = hv * Wf[t * 2 + 1];
        #pragma unroll
        for (int off = 32; off > 0; off >>= 1) {
            l0 += __shfl_down(l0, off, 64);
            l1 += __shfl_down(l1, off, 64);
        }
        if ((t & 63) == 0) { r0[t >> 6] = l0; r1[t >> 6] = l1; }
    }
    __syncthreads();
    if (t == 0) {
        float L0 = r0[0] + r0[1] + r0[2] + r0[3] + bf[0];
        float L1 = r1[0] + r1[1] + r1[2] + r1[3] + bf[1];
        float m  = fmaxf(L0, L1);
        float ls = logf(expf(L0 - m) + expf(L1 - m));
        sp01[0] = L0 - m - ls;
        sp01[1] = L1 - m - ls;
    }
    __syncthreads();

    // ---- probs writes ----
    {
        float2 p; p.x = sp01[0]; p.y = sp01[1];
        float2* out2 = (float2*)out;
        for (int e = e0 + t; e < e1; e += 512)
            out2[(size_t)b * EE + e] = p;
    }
}

extern "C" void kernel_launch(void* const* d_in, const int* in_sizes, int n_in,
                              void* d_out, int out_size, void* d_ws, size_t ws_size,
                              hipStream_t stream) {
    const float* hidden  = (const float*)d_in[0];
    const float* bboxes  = (const float*)d_in[1];
    const float* W1      = (const float*)d_in[2];
    const float* b1      = (const float*)d_in[3];
    const float* W2      = (const float*)d_in[4];
    const float* b2      = (const float*)d_in[5];
    const float* Wl1     = (const float*)d_in[6];
    const float* bl1     = (const float*)d_in[7];
    const float* Wf      = (const float*)d_in[8];
    const float* bf      = (const float*)d_in[9];
    const int*   edge    = (const int*)d_in[10];

    k_all<<<BB * GG, 512, 0, stream>>>(hidden, bboxes, edge,
                                       W1, b1, W2, b2, Wl1, bl1, Wf, bf,
                                       (float*)d_out);
}

// Round 8
// 16.862 us; speedup vs baseline: 1.9438x; 1.0815x over previous
//
#include <hip/hip_runtime.h>
#include <hip/hip_bf16.h>

// B=16, N=100, D=256, C=2, E=N*(N-1)=9900.
// Complete-graph GCN collapses to a per-batch MLP:
//   gcn_conv(x) = mean_n(x) @ W + b  (deg==100, norm==1/100, incl. self-loop)
// R7 = R6 with the nontemporal builtins applied to clang ext_vector types
// (HIP float4 is a wrapper class the builtin rejects).
//  1. Weight streams use __builtin_nontemporal_load (bypass L1 alloc) to test
//     whether the measured ~80 GB/s/CU stream ceiling is an L1-alloc artifact.
//  2. bbox-pair output writes inside k_mlp (store path overlaps read streams).
//  3. Node B is probs-only.
// Calibration: node OH ~3.2us, in-kernel cross-block barrier ~5-8us (never),
// per-CU read stream ~80 GB/s (the quantity under test).

#define BB 16
#define NN 100
#define DD 256
#define EE 9900
#define CHUNK 1238          // ceil(EE/8)

typedef float f32x4 __attribute__((ext_vector_type(4)));
typedef float f32x2 __attribute__((ext_vector_type(2)));

__device__ __forceinline__ f32x4 ldg_nt4(const float* p) {
    return __builtin_nontemporal_load(reinterpret_cast<const f32x4*>(p));
}
__device__ __forceinline__ f32x4 ld4(const float* p) {
    return *reinterpret_cast<const f32x4*>(p);
}
__device__ __forceinline__ void stg_nt4(float* p, f32x4 v) {
    __builtin_nontemporal_store(v, reinterpret_cast<f32x4*>(p));
}

__global__ __launch_bounds__(256) void k_mlp(
    const float* __restrict__ x,        // [B,N,D]
    const float* __restrict__ bboxes,   // [B,N,4]
    const int*   __restrict__ edge,     // [2,E]
    const float* __restrict__ W1, const float* __restrict__ b1,
    const float* __restrict__ W2, const float* __restrict__ b2,
    const float* __restrict__ Wl1, const float* __restrict__ bl1,
    const float* __restrict__ Wf,
    float* __restrict__ ws,             // [16][8][2] partial logits
    float* __restrict__ out)
{
    const int b  = blockIdx.x >> 3;
    const int g  = blockIdx.x & 7;
    const int t  = threadIdx.x;
    const int c4 = t & 63;          // column quad 0..63
    const int kq = t >> 6;          // 0..3

    __shared__ __align__(16) float sX[DD];
    __shared__ __align__(16) float sY[DD];
    __shared__ __align__(16) f32x4 sPf[256];
    __shared__ float sL0[8], sL1[8];

    // ---- xbar partials: 4 row-groups of 25 ----
    {
        const float* xp = x + ((size_t)b * NN + kq * 25) * DD + c4 * 4;
        f32x4 a = {0.f, 0.f, 0.f, 0.f};
        #pragma unroll
        for (int n = 0; n < 25; ++n)
            a += ld4(xp + (size_t)n * DD);
        sPf[kq * 64 + c4] = a;
    }

    // ---- bbox-pair writes for this block's edge chunk (overlaps streams) ----
    {
        const int e0 = g * CHUNK;
        const int e1 = min(e0 + CHUNK, EE);
        float* boutf = out + (size_t)BB * EE * 2;
        for (int e = e0 + t; e < e1; e += 256) {
            const int s  = edge[e];
            const int d2 = edge[EE + e];
            const size_t idx = (size_t)b * EE + e;
            f32x4 bs = ld4(bboxes + (size_t)(b * NN + s) * 4);
            f32x4 bd = ld4(bboxes + (size_t)(b * NN + d2) * 4);
            stg_nt4(boutf + idx * 8, bs);
            stg_nt4(boutf + idx * 8 + 4, bd);
        }
    }
    __syncthreads();
    if (t < 64) {
        f32x4 s = sPf[t] + sPf[64 + t] + sPf[128 + t] + sPf[192 + t];
        ((f32x4*)sX)[t] = s * 0.01f;
    }
    __syncthreads();

    // ---- layer 1: sY = relu(sX @ W1 + b1) ----
    {
        const float* Wp = W1 + (size_t)(kq * 64) * DD + c4 * 4;
        const float* xk = sX + kq * 64;
        f32x4 acc = {0.f, 0.f, 0.f, 0.f};
        #pragma unroll 8
        for (int k = 0; k < 64; ++k)
            acc += xk[k] * ldg_nt4(Wp + (size_t)k * DD);
        __syncthreads();
        sPf[kq * 64 + c4] = acc;
        __syncthreads();
        if (t < 64) {
            f32x4 s = sPf[t] + sPf[64 + t] + sPf[128 + t] + sPf[192 + t]
                    + ld4(b1 + t * 4);
            f32x4 z = {0.f, 0.f, 0.f, 0.f};
            ((f32x4*)sY)[t] = __builtin_elementwise_max(s, z);
        }
        __syncthreads();
    }

    // ---- layer 2: sX = relu(sY @ W2 + b2) ----
    {
        const float* Wp = W2 + (size_t)(kq * 64) * DD + c4 * 4;
        const float* xk = sY + kq * 64;
        f32x4 acc = {0.f, 0.f, 0.f, 0.f};
        #pragma unroll 8
        for (int k = 0; k < 64; ++k)
            acc += xk[k] * ldg_nt4(Wp + (size_t)k * DD);
        __syncthreads();
        sPf[kq * 64 + c4] = acc;
        __syncthreads();
        if (t < 64) {
            f32x4 s = sPf[t] + sPf[64 + t] + sPf[128 + t] + sPf[192 + t]
                    + ld4(b2 + t * 4);
            f32x4 z = {0.f, 0.f, 0.f, 0.f};
            ((f32x4*)sX)[t] = __builtin_elementwise_max(s, z);
        }
        __syncthreads();
    }

    // ---- layer 3 (cols [32g,32g+32)): h = relu(z2 @ (Wl1_t+Wl1_b) + bl1),
    //      partial logits for this slice ----
    {
        const int c8  = t & 7;      // col quad within slice
        const int k32 = t >> 3;     // 0..31, k-chunk of 8
        const float* Wp0 = Wl1 + (size_t)(k32 * 8) * DD + g * 32 + c8 * 4;
        const float* Wp1 = Wp0 + (size_t)DD * DD;
        const float* xk = sX + k32 * 8;
        f32x4 acc = {0.f, 0.f, 0.f, 0.f};
        #pragma unroll
        for (int k = 0; k < 8; ++k) {
            f32x4 w = ldg_nt4(Wp0 + (size_t)k * DD) + ldg_nt4(Wp1 + (size_t)k * DD);
            acc += xk[k] * w;
        }
        __syncthreads();
        sPf[k32 * 8 + c8] = acc;
        __syncthreads();
        if (t < 8) {
            f32x4 s = {0.f, 0.f, 0.f, 0.f};
            #pragma unroll
            for (int q = 0; q < 32; ++q) s += sPf[q * 8 + t];
            const int c0 = g * 32 + t * 4;
            s += ld4(bl1 + c0);
            f32x4 z = {0.f, 0.f, 0.f, 0.f};
            f32x4 h = __builtin_elementwise_max(s, z);
            sL0[t] = h.x * Wf[(c0 + 0) * 2] + h.y * Wf[(c0 + 1) * 2]
                   + h.z * Wf[(c0 + 2) * 2] + h.w * Wf[(c0 + 3) * 2];
            sL1[t] = h.x * Wf[(c0 + 0) * 2 + 1] + h.y * Wf[(c0 + 1) * 2 + 1]
                   + h.z * Wf[(c0 + 2) * 2 + 1] + h.w * Wf[(c0 + 3) * 2 + 1];
        }
        __syncthreads();
        if (t == 0) {
            float l0 = 0.f, l1 = 0.f;
            #pragma unroll
            for (int i = 0; i < 8; ++i) { l0 += sL0[i]; l1 += sL1[i]; }
            ws[(b * 8 + g) * 2 + 0] = l0;
            ws[(b * 8 + g) * 2 + 1] = l1;
        }
    }
}

// ---- Node B: assemble logits + log_softmax, write probs only ----
__global__ __launch_bounds__(256) void k_probs(
    const float* __restrict__ ws,       // [16][8][2]
    const float* __restrict__ bf,
    float* __restrict__ out)
{
    const int b = blockIdx.y;
    const int e = blockIdx.x * 256 + threadIdx.x;

    __shared__ float sp0, sp1;
    if (threadIdx.x == 0) {
        float L0 = bf[0], L1 = bf[1];
        #pragma unroll
        for (int q = 0; q < 8; ++q) {
            L0 += ws[(b * 8 + q) * 2 + 0];
            L1 += ws[(b * 8 + q) * 2 + 1];
        }
        float m  = fmaxf(L0, L1);
        float ls = logf(expf(L0 - m) + expf(L1 - m));
        sp0 = L0 - m - ls;
        sp1 = L1 - m - ls;
    }
    __syncthreads();

    if (e < EE) {
        f32x2 p = {sp0, sp1};
        __builtin_nontemporal_store(
            p, reinterpret_cast<f32x2*>(out) + (size_t)b * EE + e);
    }
}

extern "C" void kernel_launch(void* const* d_in, const int* in_sizes, int n_in,
                              void* d_out, int out_size, void* d_ws, size_t ws_size,
                              hipStream_t stream) {
    const float* hidden  = (const float*)d_in[0];
    const float* bboxes  = (const float*)d_in[1];
    const float* W1      = (const float*)d_in[2];
    const float* b1      = (const float*)d_in[3];
    const float* W2      = (const float*)d_in[4];
    const float* b2      = (const float*)d_in[5];
    const float* Wl1     = (const float*)d_in[6];
    const float* bl1     = (const float*)d_in[7];
    const float* Wf      = (const float*)d_in[8];
    const float* bf      = (const float*)d_in[9];
    const int*   edge    = (const int*)d_in[10];

    float* ws  = (float*)d_ws;      // 256 floats: partial logits
    float* out = (float*)d_out;

    k_mlp<<<BB * 8, 256, 0, stream>>>(hidden, bboxes, edge,
                                      W1, b1, W2, b2, Wl1, bl1, Wf,
                                      ws, out);

    dim3 og((EE + 255) / 256, BB);
    k_probs<<<og, 256, 0, stream>>>(ws, bf, out);
}